// Round 13
// baseline (165.865 us; speedup 1.0000x reference)
//
#include <hip/hip_runtime.h>
#include <hip/hip_fp16.h>
#include <math.h>

// Problem constants (fixed by reference setup_inputs)
#define E_ 4
#define L_ 10
#define S_ 1024
#define F_ 256
#define T_ 1024
#define NROW (E_*L_*S_)     // 40960 rows of the input GEMM
#define NBLK (NROW/64)      // 640 k0 blocks (validated 64-row split)
#define NH   48             // Fourier harmonics (cos+sin each); tail e^-11.1
#define CSW  224            // padded CS/BT row width in halves (194 live + pad)

// workspace layout (float indices). OUT aliases MT (MT dead after kF).
// ws+64..: pmin[640]. ws+2048..: pmax[640].
#define OFF_PMIN 64
#define OFF_PMAX 2048
#define OFF_M   32768                          // fp32 MT[el][f][s] (= OUT alias)
#define OFF_CS  (32768 + (size_t)NROW * F_)    // f16 CS[el][f][CSW] hi/lo pairs
#define OFF_BT  (OFF_CS + (size_t)40 * F_ * CSW / 2)   // f16 BT[t][CSW]
#define OFF_PT  (OFF_BT + (size_t)T_ * CSW / 2)        // f16 PT[256][256]

typedef _Float16 half8 __attribute__((ext_vector_type(8)));
typedef __fp16 h2v __attribute__((ext_vector_type(2)));   // cvt_pkrtz result type
typedef float f32x4v __attribute__((ext_vector_type(4)));

__device__ __forceinline__ void put_hl(_Float16* p, float v) {
  _Float16 h = (_Float16)v;
  _Float16 l = (_Float16)(v - (float)h);
  p[0] = h; p[1] = l;
}

// R13: per-wave global-range reduction (replaces the k1 launch). All lanes
// end with identical left/right. min/max is exactly associative ->
// bit-identical to k1's result regardless of reduction order.
__device__ __forceinline__ void wave_range(const float* __restrict__ pmin,
                                           const float* __restrict__ pmax,
                                           float& left, float& right) {
  const int lane = threadIdx.x & 63;
  float vmin = 3.4e38f, vmax = -3.4e38f;
  for (int i = lane; i < NBLK; i += 64) {
    vmin = fminf(vmin, pmin[i]);
    vmax = fmaxf(vmax, pmax[i]);
  }
#pragma unroll
  for (int off = 32; off; off >>= 1) {
    vmin = fminf(vmin, __shfl_xor(vmin, off));
    vmax = fmaxf(vmax, __shfl_xor(vmax, off));
  }
  left = vmin; right = vmax;
}

// Packed RTZ f32->2xf16 store into XOR-swizzled [16][128] LDS plane.
// half-index = row*128 + (2*lane ^ ((row&7)<<3)): 16B-granule swizzle so
// ds_read_b128 fragment reads spread evenly over banks.
__device__ __forceinline__ void stpk(_Float16* b, int row, int lane,
                                     float x, float y) {
  const int hi = row * 128 + ((2 * lane) ^ ((row & 7) << 3));
  *(h2v*)(b + hi) = __builtin_amdgcn_cvt_pkrtz(x, y);
}
// RNE pair store (hi-only planes): scalar casts round-to-nearest-even,
// halving the RTZ max error (B is hi-only since R9 — error budget in kF).
__device__ __forceinline__ void stpk_rne(_Float16* b, int row, int lane,
                                         float x, float y) {
  const int hi = row * 128 + ((2 * lane) ^ ((row & 7) << 3));
  h2v v;
  v[0] = (__fp16)x;
  v[1] = (__fp16)y;
  *(h2v*)(b + hi) = v;
}

// K_pt: PT[c][k] = (f16)P[k][c]. Writes ALL of PT -> no memset needed.
__global__ __launch_bounds__(256) void k_pt(const float* __restrict__ P,
                                            _Float16* __restrict__ PT) {
  const int k = blockIdx.x;
  const int c = threadIdx.x;
  PT[(size_t)c * F_ + k] = (_Float16)P[(size_t)k * F_ + c];
}

// K0: m = matrix @ params via MFMA f16 hi/lo split; writes M TRANSPOSED:
// MT[el][f][s]. R3: zero global atomics (per-block partials).
// Validated 64-row/640-block R10 shape (R11's 32-row split regressed).
__global__ __launch_bounds__(256) void k0_mfma(const float* __restrict__ A,
                                               const _Float16* __restrict__ PT,
                                               float* __restrict__ MT,
                                               float* __restrict__ pmin,
                                               float* __restrict__ pmax) {
  __shared__ __align__(16) _Float16 Ahi[64][40];
  __shared__ __align__(16) _Float16 Alo[64][40];
  __shared__ __align__(16) _Float16 Bl[256][40];
  __shared__ float wmin[4], wmax[4];
  const int tid = threadIdx.x;
  const int wave = tid >> 6, lane = tid & 63;
  const int nn = lane & 15, quad = lane >> 4;
  const int row0 = blockIdx.x * 64;
  const int el = blockIdx.x >> 4;
  const int s0 = (blockIdx.x & 15) * 64;
  const int r = tid >> 2, part = tid & 3;
  const float* asrc = A + (size_t)(row0 + r) * F_ + part * 8;
  const _Float16* bbase = PT + (size_t)tid * F_;
  f32x4v acc[4][4];
#pragma unroll
  for (int rt = 0; rt < 4; ++rt)
#pragma unroll
    for (int ct = 0; ct < 4; ++ct) acc[rt][ct] = (f32x4v){0.f, 0.f, 0.f, 0.f};

  // prefetch chunk 0 into registers
  float4 pa0 = ((const float4*)asrc)[0];
  float4 pa1 = ((const float4*)asrc)[1];
  int4 pb0, pb1, pb2, pb3;
  {
    const int4* bs = (const int4*)bbase;
    pb0 = bs[0]; pb1 = bs[1]; pb2 = bs[2]; pb3 = bs[3];
  }

  for (int kc = 0; kc < 8; ++kc) {
    __syncthreads();   // prior chunk's fragment reads complete; LDS reusable
    {
      float vv[8] = {pa0.x, pa0.y, pa0.z, pa0.w, pa1.x, pa1.y, pa1.z, pa1.w};
      half8 hh, hl;
#pragma unroll
      for (int j = 0; j < 8; ++j) {
        _Float16 h = (_Float16)vv[j];
        hh[j] = h;
        hl[j] = (_Float16)(vv[j] - (float)h);
      }
      *(half8*)&Ahi[r][part * 8] = hh;
      *(half8*)&Alo[r][part * 8] = hl;
      int4* bd = (int4*)&Bl[tid][0];
      bd[0] = pb0; bd[1] = pb1; bd[2] = pb2; bd[3] = pb3;
    }
    if (kc < 7) {
      const float* an = asrc + (kc + 1) * 32;
      pa0 = ((const float4*)an)[0];
      pa1 = ((const float4*)an)[1];
      const int4* bn = (const int4*)(bbase + (kc + 1) * 32);
      pb0 = bn[0]; pb1 = bn[1]; pb2 = bn[2]; pb3 = bn[3];
    }
    __syncthreads();   // LDS tile visible
    half8 afh[4], afl[4], bf[4];
#pragma unroll
    for (int rt = 0; rt < 4; ++rt) {
      afh[rt] = *(const half8*)&Ahi[rt * 16 + nn][quad * 8];
      afl[rt] = *(const half8*)&Alo[rt * 16 + nn][quad * 8];
    }
#pragma unroll
    for (int ct = 0; ct < 4; ++ct)
      bf[ct] = *(const half8*)&Bl[wave * 64 + ct * 16 + nn][quad * 8];
#pragma unroll
    for (int rt = 0; rt < 4; ++rt)
#pragma unroll
      for (int ct = 0; ct < 4; ++ct) {
        acc[rt][ct] = __builtin_amdgcn_mfma_f32_16x16x32_f16(afh[rt], bf[ct], acc[rt][ct], 0, 0, 0);
        acc[rt][ct] = __builtin_amdgcn_mfma_f32_16x16x32_f16(afl[rt], bf[ct], acc[rt][ct], 0, 0, 0);
      }
  }
  float vmin = 3.4e38f, vmax = -3.4e38f;
#pragma unroll
  for (int rt = 0; rt < 4; ++rt)
#pragma unroll
    for (int ct = 0; ct < 4; ++ct) {
      f32x4v c = acc[rt][ct];
      const int col = wave * 64 + ct * 16 + nn;
      const int sl = s0 + rt * 16 + quad * 4;
      *(float4*)&MT[((size_t)el * F_ + col) * S_ + sl] =
          make_float4(c[0], c[1], c[2], c[3]);
      vmin = fminf(vmin, fminf(fminf(c[0], c[1]), fminf(c[2], c[3])));
      vmax = fmaxf(vmax, fmaxf(fmaxf(c[0], c[1]), fmaxf(c[2], c[3])));
    }
#pragma unroll
  for (int off = 32; off; off >>= 1) {
    vmin = fminf(vmin, __shfl_down(vmin, off));
    vmax = fmaxf(vmax, __shfl_down(vmax, off));
  }
  if (lane == 0) { wmin[wave] = vmin; wmax[wave] = vmax; }
  __syncthreads();
  if (tid == 0) {
    pmin[blockIdx.x] = fminf(fminf(wmin[0], wmin[1]), fminf(wmin[2], wmin[3]));
    pmax[blockIdx.x] = fmaxf(fmaxf(wmax[0], wmax[1]), fmaxf(wmax[2], wmax[3]));
  }
}

// KBF (R13): merged kB + kF — both depend only on pmin/pmax (+MT for kF),
// so they share one launch. Each wave recomputes the global range
// (wave_range). Blocks [0,1024): kB basis matrix. Blocks [1024,3584):
// kF, 4 waves/block, one (el,f) per wave, per-wave 8KB LDS planes (no
// cross-wave sharing -> still zero barriers in the kF path).
__global__ __launch_bounds__(256) void kBF(const float* __restrict__ pmin,
                                           const float* __restrict__ pmax,
                                           _Float16* __restrict__ BT,
                                           const float* __restrict__ MT,
                                           _Float16* __restrict__ CS) {
  __shared__ __align__(16) _Float16 AhS[4][16 * 128];
  __shared__ __align__(16) _Float16 BhS[4][16 * 128];
  float left, right;
  wave_range(pmin, pmax, left, right);
  const float Pp = (right - left) + 5.0f;       // period (alias gap > 2.4)
  const float w1 = 6.2831853071795864f / Pp;    // omega1

  if (blockIdx.x < T_) {
    // ---- kB: basis matrix BT[t][j], j=2*kidx(+1): kidx 0=DC,
    // 1..48=a_k cos(w_k x_t), 49..96=a_k sin. Writes ALL j<CSW.
    const int t = blockIdx.x;
    const int j = threadIdx.x;
    if (j >= CSW) return;
    const float dg = (right - left) / 1023.0f;
    const float sqpi8 = 0.62665706865775006f;   // sqrt(pi/8)
    const float asc = 2.0f * sqpi8 / Pp;
    const float a0 = sqpi8 / Pp;
    const float x = left + (float)t * dg;
    float v = 0.f;
    const int kidx = j >> 1;
    if (j < 2 * (2 * NH + 1)) {
      if (kidx == 0) v = a0;
      else if (kidx <= NH) {
        float wk = w1 * (float)kidx;
        v = asc * expf(-wk * wk * 0.03125f) * __cosf(wk * x);
      } else {
        float wk = w1 * (float)(kidx - NH);
        v = asc * expf(-wk * wk * 0.03125f) * __sinf(wk * x);
      }
    }
    BT[(size_t)t * CSW + j] = (_Float16)v;
    return;
  }

  // ---- kF: Fourier sums via MFMA with angle addition k=8q+r (A rows
  // cos/sin(8q a), B rows cos/sin(r a); C_{8q+r}=G[2q][2r]-G[2q+1][2r+1],
  // S_{8q+r}=G[2q+1][2r]+G[2q][2r+1]). One wave per (el,f).
  const int wave = threadIdx.x >> 6;
  const int lane = threadIdx.x & 63;
  const int fi = (blockIdx.x - T_) * 4 + wave;   // 0..10239
  const int el = fi >> 8;
  const int f = fi & 255;
  const float* src = MT + ((size_t)el * F_ + f) * S_;
  _Float16* csrow = CS + ((size_t)el * F_ + f) * CSW;
  _Float16* Ah = AhS[wave];
  _Float16* Bh = BhS[wave];

  // constant rows, once: A q=0 (cos0=1,sin0=0); A rows 14,15 zero; B r=0.
  stpk(Ah, 0, lane, 1.f, 1.f);
  stpk(Ah, 1, lane, 0.f, 0.f);
  stpk(Ah, 14, lane, 0.f, 0.f);
  stpk(Ah, 15, lane, 0.f, 0.f);
  stpk(Bh, 0, lane, 1.f, 1.f);
  stpk(Bh, 1, lane, 0.f, 0.f);

  f32x4v acc = (f32x4v){0.f, 0.f, 0.f, 0.f};
  const int rw = lane & 15, quad = lane >> 4;

  float2 nxt = ((const float2*)src)[lane];
  for (int bt = 0; bt < 8; ++bt) {        // 8 batches x 128 samples
    float2 cur = nxt;
    if (bt < 7) nxt = ((const float2*)src)[(bt + 1) * 64 + lane];
    // two samples (2*lane, 2*lane+1) in lockstep; pack pairs into b32 writes
    float aa = w1 * cur.x, ab = w1 * cur.y;
    float s1a, c1a, s1b, c1b;
    __sincosf(aa, &s1a, &c1a);
    __sincosf(ab, &s1b, &c1b);
    const float tca = c1a + c1a, tcb = c1b + c1b;
    stpk_rne(Bh, 2, lane, c1a, c1b);           // r=1 cos
    stpk_rne(Bh, 3, lane, s1a, s1b);           // r=1 sin
    float cpa = c1a, cppa = 1.f, spa = s1a, sppa = 0.f;
    float cpb = c1b, cppb = 1.f, spb = s1b, sppb = 0.f;
    float c2a = 0.f, c2b = 0.f, s2a = 0.f, s2b = 0.f;
#pragma unroll
    for (int rr = 2; rr <= 7; ++rr) {          // Chebyshev: cos/sin(r*a)
      float cna = fmaf(tca, cpa, -cppa);
      float cnb = fmaf(tcb, cpb, -cppb);
      float sna = fmaf(tca, spa, -sppa);
      float snb = fmaf(tcb, spb, -sppb);
      if (rr == 2) { c2a = cna; c2b = cnb; s2a = sna; s2b = snb; }
      stpk_rne(Bh, 2 * rr, lane, cna, cnb);
      stpk_rne(Bh, 2 * rr + 1, lane, sna, snb);
      cppa = cpa; cpa = cna; cppb = cpb; cpb = cnb;
      sppa = spa; spa = sna; sppb = spb; spb = snb;
    }
    // q-side: cos/sin(8a) by doubling from (c2,s2)
    float d2a = c2a + c2a, d2b = c2b + c2b;
    float c4a = fmaf(d2a, c2a, -1.f), c4b = fmaf(d2b, c2b, -1.f);
    float s4a = d2a * s2a, s4b = d2b * s2b;
    float d4a = c4a + c4a, d4b = c4b + c4b;
    float c8a = fmaf(d4a, c4a, -1.f), c8b = fmaf(d4b, c4b, -1.f);
    float s8a = d4a * s4a, s8b = d4b * s4b;
    stpk_rne(Ah, 2, lane, c8a, c8b);           // q=1
    stpk_rne(Ah, 3, lane, s8a, s8b);
    const float tqa = c8a + c8a, tqb = c8b + c8b;
    float qca = c8a, qcpa = 1.f, qsa = s8a, qspa = 0.f;
    float qcb = c8b, qcpb = 1.f, qsb = s8b, qspb = 0.f;
#pragma unroll
    for (int q = 2; q <= 6; ++q) {             // Chebyshev: cos/sin(8q*a)
      float cna = fmaf(tqa, qca, -qcpa);
      float cnb = fmaf(tqb, qcb, -qcpb);
      float sna = fmaf(tqa, qsa, -qspa);
      float snb = fmaf(tqb, qsb, -qspb);
      stpk_rne(Ah, 2 * q, lane, cna, cnb);
      stpk_rne(Ah, 2 * q + 1, lane, sna, snb);
      qcpa = qca; qca = cna; qcpb = qcb; qcb = cnb;
      qspa = qsa; qsa = sna; qspb = qsb; qsb = snb;
    }
    // MFMA over this batch's K=128 (per-wave LDS -> no barrier; compiler
    // inserts lgkmcnt waits for the RAW dependency)
#pragma unroll
    for (int kc = 0; kc < 4; ++kc) {
      const int off = rw * 128 + ((kc * 32 + quad * 8) ^ ((rw & 7) << 3));
      half8 af = *(const half8*)(Ah + off);
      half8 bhf = *(const half8*)(Bh + off);
      acc = __builtin_amdgcn_mfma_f32_16x16x32_f16(af, bhf, acc, 0, 0, 0);
    }
  }
  // extraction: lane holds G[4u+i][c], u=lane>>4, c=lane&15.
  // pair col 2r (even lane) with col 2r+1 (odd lane) via shfl_xor(1).
  float a0v = acc[0], a1v = acc[1], a2v = acc[2], a3v = acc[3];
  float p0 = __shfl_xor(a0v, 1), p1 = __shfl_xor(a1v, 1);
  float p2 = __shfl_xor(a2v, 1), p3 = __shfl_xor(a3v, 1);
  if ((rw & 1) == 0) {
    const int rr = rw >> 1;
    const int k0v = 16 * quad + rr;        // q = 2u
    const int k1v = 16 * quad + 8 + rr;    // q = 2u+1
    float C0 = a0v - p1, S0 = a1v + p0;    // G[2q][2r]-G[2q+1][2r+1], ...
    float C1 = a2v - p3, S1 = a3v + p2;
    if (k0v == 0) {
      csrow[0] = (_Float16)1024.f;         // DC exact
      csrow[1] = (_Float16)0.f;
    }
    if (k0v >= 1 && k0v <= NH) {
      put_hl(csrow + 2 * k0v, C0);
      put_hl(csrow + 2 * (NH + k0v), S0);
    }
    if (k1v <= NH) {
      put_hl(csrow + 2 * k1v, C1);
      put_hl(csrow + 2 * (NH + k1v), S1);
    }
  }
  // zero the pad columns (194..223) so kR's full-width reads are
  // deterministic without the 4.6MB CS memset. 15 x 4B stores, lanes 0-14.
  if (lane < 15) {
    h2v z;
    z[0] = (__fp16)0.f;
    z[1] = (__fp16)0.f;
    *(h2v*)(csrow + 194 + 2 * lane) = z;
  }
}

// KR: reconstruction GEMM ksum = CS x BT^T via MFMA (7 K-chunks of 32).
// R2: ZERO-LDS / ZERO-BARRIER, direct-fragment-load (16B-aligned rows).
__global__ __launch_bounds__(256) void kR(const _Float16* __restrict__ CS,
                                          const _Float16* __restrict__ BT,
                                          float* __restrict__ OUT) {
  const int tid = threadIdx.x;
  const int wave = tid >> 6, lane = tid & 63;
  const int nn = lane & 15, quad = lane >> 4;
  const int el = blockIdx.x >> 4;
  const int t0 = (blockIdx.x & 15) << 6;

  const _Float16* ab0 = CS + ((size_t)el * F_ + wave * 64 + 0 * 16 + nn) * CSW + quad * 8;
  const _Float16* ab1 = CS + ((size_t)el * F_ + wave * 64 + 1 * 16 + nn) * CSW + quad * 8;
  const _Float16* ab2 = CS + ((size_t)el * F_ + wave * 64 + 2 * 16 + nn) * CSW + quad * 8;
  const _Float16* ab3 = CS + ((size_t)el * F_ + wave * 64 + 3 * 16 + nn) * CSW + quad * 8;
  const _Float16* bb0 = BT + (size_t)(t0 + 0 * 16 + nn) * CSW + quad * 8;
  const _Float16* bb1 = BT + (size_t)(t0 + 1 * 16 + nn) * CSW + quad * 8;
  const _Float16* bb2 = BT + (size_t)(t0 + 2 * 16 + nn) * CSW + quad * 8;
  const _Float16* bb3 = BT + (size_t)(t0 + 3 * 16 + nn) * CSW + quad * 8;

  f32x4v acc[4][4];
#pragma unroll
  for (int ft = 0; ft < 4; ++ft)
#pragma unroll
    for (int tn = 0; tn < 4; ++tn) acc[ft][tn] = (f32x4v){0.f, 0.f, 0.f, 0.f};

  half8 pa[4], pb[4];
  pa[0] = *(const half8*)ab0; pa[1] = *(const half8*)ab1;
  pa[2] = *(const half8*)ab2; pa[3] = *(const half8*)ab3;
  pb[0] = *(const half8*)bb0; pb[1] = *(const half8*)bb1;
  pb[2] = *(const half8*)bb2; pb[3] = *(const half8*)bb3;

#pragma unroll
  for (int kc = 0; kc < CSW / 32; ++kc) {
    half8 af[4], bf[4];
#pragma unroll
    for (int ft = 0; ft < 4; ++ft) af[ft] = pa[ft];
#pragma unroll
    for (int tn = 0; tn < 4; ++tn) bf[tn] = pb[tn];
    if (kc < CSW / 32 - 1) {
      const int o = (kc + 1) * 32;
      pa[0] = *(const half8*)(ab0 + o); pa[1] = *(const half8*)(ab1 + o);
      pa[2] = *(const half8*)(ab2 + o); pa[3] = *(const half8*)(ab3 + o);
      pb[0] = *(const half8*)(bb0 + o); pb[1] = *(const half8*)(bb1 + o);
      pb[2] = *(const half8*)(bb2 + o); pb[3] = *(const half8*)(bb3 + o);
    }
#pragma unroll
    for (int ft = 0; ft < 4; ++ft)
#pragma unroll
      for (int tn = 0; tn < 4; ++tn)
        acc[ft][tn] = __builtin_amdgcn_mfma_f32_16x16x32_f16(af[ft], bf[tn], acc[ft][tn], 0, 0, 0);
  }

  float* Ob = OUT + (size_t)el * F_ * T_ + t0;
#pragma unroll
  for (int ft = 0; ft < 4; ++ft)
#pragma unroll
    for (int tn = 0; tn < 4; ++tn) {
      f32x4v c = acc[ft][tn];
      const int fb = wave * 64 + ft * 16 + quad * 4;
      const int tc = tn * 16 + nn;
      Ob[(size_t)(fb + 0) * T_ + tc] = c[0];
      Ob[(size_t)(fb + 1) * T_ + tc] = c[1];
      Ob[(size_t)(fb + 2) * T_ + tc] = c[2];
      Ob[(size_t)(fb + 3) * T_ + tc] = c[3];
    }
}

// K4: epilogue. R13: recomputes left/dg/scale per wave (k1 deleted).
__global__ __launch_bounds__(256) void k4_epi(const float* __restrict__ OUT,
                                              const float* __restrict__ pmin,
                                              const float* __restrict__ pmax,
                                              const float* __restrict__ dl,
                                              float* __restrict__ out) {
  __shared__ float rs[4][6];
  const int tid = threadIdx.x;
  const int l = blockIdx.x >> 8;
  const int f = blockIdx.x & 255;
  float left, right;
  wave_range(pmin, pmax, left, right);
  const float dg = (right - left) / 1023.0f;
  const float delta = (right - left) / 1024.0f;
  const float scale = delta * 0.5f / 0.62665706865775006f;
  const int t = 4 * tid;
  float etv[4];
#pragma unroll
  for (int d = 0; d < 4; ++d) {
    float x = left + (float)(t + d) * dg;
    etv[d] = expf(-8.0f * x * x);
  }
  float red[E_][4];
#pragma unroll
  for (int e = 0; e < E_; ++e) {
    float4 ks = *(const float4*)(OUT + (((size_t)(e * L_ + l)) * F_ + f) * T_ + t);
    const float dlv = dl[e * L_ + l];
    const float zc = (float)S_ - dlv;
    const float idl = 1.0f / dlv;
    red[e][0] = (ks.x - zc * etv[0]) * idl;
    red[e][1] = (ks.y - zc * etv[1]) * idl;
    red[e][2] = (ks.z - zc * etv[2]) * idl;
    red[e][3] = (ks.w - zc * etv[3]) * idl;
  }
  float D[6];
  const int pa[6] = {0, 0, 0, 1, 1, 2};
  const int pb[6] = {1, 2, 3, 2, 3, 3};
#pragma unroll
  for (int p = 0; p < 6; ++p) {
    float s = 0.f;
#pragma unroll
    for (int d = 0; d < 4; ++d) s += fabsf(red[pa[p]][d] - red[pb[p]][d]);
    D[p] = s;
  }
#pragma unroll
  for (int off = 32; off; off >>= 1)
#pragma unroll
    for (int p = 0; p < 6; ++p) D[p] += __shfl_down(D[p], off);
  if ((tid & 63) == 0) {
#pragma unroll
    for (int p = 0; p < 6; ++p) rs[tid >> 6][p] = D[p];
  }
  __syncthreads();
  if (tid == 0) {
    float Tp[6];
#pragma unroll
    for (int p = 0; p < 6; ++p)
      Tp[p] = (rs[0][p] + rs[1][p] + rs[2][p] + rs[3][p]) * scale;
    float test = Tp[0];
#pragma unroll
    for (int p = 1; p < 6; ++p) test = fmaxf(test, Tp[p]);
    float train = fmaxf(fmaxf(Tp[1], Tp[2]), Tp[5]);
    out[l * F_ + f] = train;
    out[L_ * F_ + l * F_ + f] = test;
  }
}

extern "C" void kernel_launch(void* const* d_in, const int* in_sizes, int n_in,
                              void* d_out, int out_size, void* d_ws, size_t ws_size,
                              hipStream_t stream) {
  const float* A  = (const float*)d_in[0];   // matrix (4,10,1024,256)
  const float* dl = (const float*)d_in[1];   // data_len (4,10)
  const float* P  = (const float*)d_in[2];   // params (256,256)
  float* out = (float*)d_out;
  float* ws = (float*)d_ws;
  float* pmin = ws + OFF_PMIN;               // 640 per-block minima
  float* pmax = ws + OFF_PMAX;               // 640 per-block maxima
  float* MT  = ws + OFF_M;                   // fp32 GEMM result (dead after kBF)
  float* OUT = ws + OFF_M;                   // OUT aliases MT
  _Float16* CS = (_Float16*)(ws + OFF_CS);
  _Float16* BT = (_Float16*)(ws + OFF_BT);
  _Float16* PT = (_Float16*)(ws + OFF_PT);

  // No memsets: PT fully written by k_pt; BT fully written by kBF(kB part);
  // CS live region + pad cols written by kBF(kF part); pmin/pmax fully
  // written by k0 before consumers read.
  // R13: 5 launches (was 7) — k1 folded into per-wave wave_range in
  // consumers; kB merged into kBF.
  k_pt<<<F_, 256, 0, stream>>>(P, PT);
  k0_mfma<<<NBLK, 256, 0, stream>>>(A, PT, MT, pmin, pmax);
  kBF<<<T_ + (E_ * L_ * F_) / 4, 256, 0, stream>>>(pmin, pmax, BT, MT, CS);
  kR<<<(E_ * L_) * 16, 256, 0, stream>>>(CS, BT, OUT);
  k4_epi<<<L_ * F_, 256, 0, stream>>>(OUT, pmin, pmax, dl, out);
}

// Round 14
// 159.188 us; speedup vs baseline: 1.0419x; 1.0419x over previous
//
#include <hip/hip_runtime.h>
#include <hip/hip_fp16.h>
#include <math.h>

// Problem constants (fixed by reference setup_inputs)
#define E_ 4
#define L_ 10
#define S_ 1024
#define F_ 256
#define T_ 1024
#define NROW (E_*L_*S_)     // 40960 rows of the input GEMM
#define NBLK (NROW/64)      // 640 k0 blocks (validated 64-row split)
#define NH   48             // Fourier harmonics (cos+sin each); tail e^-11.1
#define CSW  224            // padded CS/BT row width in halves (194 live + pad)

// workspace layout (float indices). OUT aliases MT (MT dead after kF).
// ws+0..15: hdr. ws+64..: pmin[640]. ws+2048..: pmax[640].
#define OFF_PMIN 64
#define OFF_PMAX 2048
#define OFF_M   32768                          // fp32 MT[el][f][s] (= OUT alias)
#define OFF_CS  (32768 + (size_t)NROW * F_)    // f16 CS[el][f][CSW] hi/lo pairs
#define OFF_BT  (OFF_CS + (size_t)40 * F_ * CSW / 2)   // f16 BT[t][CSW]
#define OFF_PT  (OFF_BT + (size_t)T_ * CSW / 2)        // f16 PT[256][256]

typedef _Float16 half8 __attribute__((ext_vector_type(8)));
typedef __fp16 h2v __attribute__((ext_vector_type(2)));   // cvt_pkrtz result type
typedef float f32x4v __attribute__((ext_vector_type(4)));

__device__ __forceinline__ void put_hl(_Float16* p, float v) {
  _Float16 h = (_Float16)v;
  _Float16 l = (_Float16)(v - (float)h);
  p[0] = h; p[1] = l;
}

// Packed RTZ f32->2xf16 store into XOR-swizzled [16][128] LDS plane.
// half-index = row*128 + (2*lane ^ ((row&7)<<3)): 16B-granule swizzle so
// ds_read_b128 fragment reads spread evenly over banks.
__device__ __forceinline__ void stpk(_Float16* b, int row, int lane,
                                     float x, float y) {
  const int hi = row * 128 + ((2 * lane) ^ ((row & 7) << 3));
  *(h2v*)(b + hi) = __builtin_amdgcn_cvt_pkrtz(x, y);
}
// RNE pair store (hi-only planes): scalar casts round-to-nearest-even,
// halving the RTZ max error (B is hi-only since R9 — error budget in kF).
__device__ __forceinline__ void stpk_rne(_Float16* b, int row, int lane,
                                         float x, float y) {
  const int hi = row * 128 + ((2 * lane) ^ ((row & 7) << 3));
  h2v v;
  v[0] = (__fp16)x;
  v[1] = (__fp16)y;
  *(h2v*)(b + hi) = v;
}

// K_pt: PT[c][k] = (f16)P[k][c]. Writes ALL of PT -> no memset needed.
__global__ __launch_bounds__(256) void k_pt(const float* __restrict__ P,
                                            _Float16* __restrict__ PT) {
  const int k = blockIdx.x;
  const int c = threadIdx.x;
  PT[(size_t)c * F_ + k] = (_Float16)P[(size_t)k * F_ + c];
}

// K0: m = matrix @ params via MFMA f16 hi/lo split; writes M TRANSPOSED:
// MT[el][f][s]. R3: zero global atomics (per-block partials, k1 reduces).
// Validated 64-row/640-block shape (R11's 32-row split regressed: B
// staging doubled, barrier train amortized worse).
__global__ __launch_bounds__(256) void k0_mfma(const float* __restrict__ A,
                                               const _Float16* __restrict__ PT,
                                               float* __restrict__ MT,
                                               float* __restrict__ pmin,
                                               float* __restrict__ pmax) {
  __shared__ __align__(16) _Float16 Ahi[64][40];
  __shared__ __align__(16) _Float16 Alo[64][40];
  __shared__ __align__(16) _Float16 Bl[256][40];
  __shared__ float wmin[4], wmax[4];
  const int tid = threadIdx.x;
  const int wave = tid >> 6, lane = tid & 63;
  const int nn = lane & 15, quad = lane >> 4;
  const int row0 = blockIdx.x * 64;
  const int el = blockIdx.x >> 4;
  const int s0 = (blockIdx.x & 15) * 64;
  const int r = tid >> 2, part = tid & 3;
  const float* asrc = A + (size_t)(row0 + r) * F_ + part * 8;
  const _Float16* bbase = PT + (size_t)tid * F_;
  f32x4v acc[4][4];
#pragma unroll
  for (int rt = 0; rt < 4; ++rt)
#pragma unroll
    for (int ct = 0; ct < 4; ++ct) acc[rt][ct] = (f32x4v){0.f, 0.f, 0.f, 0.f};

  // prefetch chunk 0 into registers
  float4 pa0 = ((const float4*)asrc)[0];
  float4 pa1 = ((const float4*)asrc)[1];
  int4 pb0, pb1, pb2, pb3;
  {
    const int4* bs = (const int4*)bbase;
    pb0 = bs[0]; pb1 = bs[1]; pb2 = bs[2]; pb3 = bs[3];
  }

  for (int kc = 0; kc < 8; ++kc) {
    __syncthreads();   // prior chunk's fragment reads complete; LDS reusable
    {
      float vv[8] = {pa0.x, pa0.y, pa0.z, pa0.w, pa1.x, pa1.y, pa1.z, pa1.w};
      half8 hh, hl;
#pragma unroll
      for (int j = 0; j < 8; ++j) {
        _Float16 h = (_Float16)vv[j];
        hh[j] = h;
        hl[j] = (_Float16)(vv[j] - (float)h);
      }
      *(half8*)&Ahi[r][part * 8] = hh;
      *(half8*)&Alo[r][part * 8] = hl;
      int4* bd = (int4*)&Bl[tid][0];
      bd[0] = pb0; bd[1] = pb1; bd[2] = pb2; bd[3] = pb3;
    }
    if (kc < 7) {
      const float* an = asrc + (kc + 1) * 32;
      pa0 = ((const float4*)an)[0];
      pa1 = ((const float4*)an)[1];
      const int4* bn = (const int4*)(bbase + (kc + 1) * 32);
      pb0 = bn[0]; pb1 = bn[1]; pb2 = bn[2]; pb3 = bn[3];
    }
    __syncthreads();   // LDS tile visible
    half8 afh[4], afl[4], bf[4];
#pragma unroll
    for (int rt = 0; rt < 4; ++rt) {
      afh[rt] = *(const half8*)&Ahi[rt * 16 + nn][quad * 8];
      afl[rt] = *(const half8*)&Alo[rt * 16 + nn][quad * 8];
    }
#pragma unroll
    for (int ct = 0; ct < 4; ++ct)
      bf[ct] = *(const half8*)&Bl[wave * 64 + ct * 16 + nn][quad * 8];
#pragma unroll
    for (int rt = 0; rt < 4; ++rt)
#pragma unroll
      for (int ct = 0; ct < 4; ++ct) {
        acc[rt][ct] = __builtin_amdgcn_mfma_f32_16x16x32_f16(afh[rt], bf[ct], acc[rt][ct], 0, 0, 0);
        acc[rt][ct] = __builtin_amdgcn_mfma_f32_16x16x32_f16(afl[rt], bf[ct], acc[rt][ct], 0, 0, 0);
      }
  }
  float vmin = 3.4e38f, vmax = -3.4e38f;
#pragma unroll
  for (int rt = 0; rt < 4; ++rt)
#pragma unroll
    for (int ct = 0; ct < 4; ++ct) {
      f32x4v c = acc[rt][ct];
      const int col = wave * 64 + ct * 16 + nn;
      const int sl = s0 + rt * 16 + quad * 4;
      *(float4*)&MT[((size_t)el * F_ + col) * S_ + sl] =
          make_float4(c[0], c[1], c[2], c[3]);
      vmin = fminf(vmin, fminf(fminf(c[0], c[1]), fminf(c[2], c[3])));
      vmax = fmaxf(vmax, fmaxf(fmaxf(c[0], c[1]), fmaxf(c[2], c[3])));
    }
#pragma unroll
  for (int off = 32; off; off >>= 1) {
    vmin = fminf(vmin, __shfl_down(vmin, off));
    vmax = fmaxf(vmax, __shfl_down(vmax, off));
  }
  if (lane == 0) { wmin[wave] = vmin; wmax[wave] = vmax; }
  __syncthreads();
  if (tid == 0) {
    pmin[blockIdx.x] = fminf(fminf(wmin[0], wmin[1]), fminf(wmin[2], wmin[3]));
    pmax[blockIdx.x] = fmaxf(fmaxf(wmax[0], wmax[1]), fmaxf(wmax[2], wmax[3]));
  }
}

// K1: final min/max reduction over 640 per-block partials + grid/Fourier
// constants. Single block, 256 threads — replaces all global atomics.
// R13's fusion of this into consumers cost +3.4us (wave_range overhead in
// ~6100 blocks + coarser kF blocks) — kept as its own tiny launch.
__global__ __launch_bounds__(256) void k1_setup(const float* __restrict__ pmin,
                                                const float* __restrict__ pmax,
                                                float* __restrict__ hdr) {
  __shared__ float sm[4], sx[4];
  const int tid = threadIdx.x;
  float vmin = 3.4e38f, vmax = -3.4e38f;
  for (int i = tid; i < NBLK; i += 256) {
    vmin = fminf(vmin, pmin[i]);
    vmax = fmaxf(vmax, pmax[i]);
  }
#pragma unroll
  for (int off = 32; off; off >>= 1) {
    vmin = fminf(vmin, __shfl_down(vmin, off));
    vmax = fmaxf(vmax, __shfl_down(vmax, off));
  }
  if ((tid & 63) == 0) { sm[tid >> 6] = vmin; sx[tid >> 6] = vmax; }
  __syncthreads();
  if (tid == 0) {
    const float left = fminf(fminf(sm[0], sm[1]), fminf(sm[2], sm[3]));
    const float right = fmaxf(fmaxf(sx[0], sx[1]), fmaxf(sx[2], sx[3]));
    const float dg = (right - left) / 1023.0f;
    const float delta = (right - left) / 1024.0f;
    const float divisor = 0.62665706865775006f;   // sqrt(2*pi)*0.25
    const float scale = delta * 0.5f / divisor;
    const float Pp = (right - left) + 5.0f;       // period (alias gap > 2.4)
    const float sqpi8 = 0.62665706865775006f;     // sqrt(pi/8)
    hdr[0] = left; hdr[1] = dg; hdr[2] = 0.f; hdr[3] = scale;
    hdr[4] = 6.2831853071795864f / Pp;            // omega1
    hdr[5] = 2.0f * sqpi8 / Pp;                   // a_k scale
    hdr[6] = sqpi8 / Pp;                          // a_0
  }
}

// KB: basis matrix BT[t][j]. Writes ALL j<CSW (v=0 for j>=194) -> no memset.
__global__ __launch_bounds__(256) void kB(const float* __restrict__ hdr,
                                          _Float16* __restrict__ BT) {
  const int t = blockIdx.x;
  const int j = threadIdx.x;
  if (j >= CSW) return;
  const float left = hdr[0], dg = hdr[1];
  const float w1 = hdr[4], asc = hdr[5], a0 = hdr[6];
  const float x = left + (float)t * dg;
  float v = 0.f;
  const int kidx = j >> 1;
  if (j < 2 * (2 * NH + 1)) {
    if (kidx == 0) v = a0;
    else if (kidx <= NH) {
      float wk = w1 * (float)kidx;
      v = asc * expf(-wk * wk * 0.03125f) * __cosf(wk * x);
    } else {
      float wk = w1 * (float)(kidx - NH);
      v = asc * expf(-wk * wk * 0.03125f) * __sinf(wk * x);
    }
  }
  BT[(size_t)t * CSW + j] = (_Float16)v;
}

// KF (R7 structure; R9: B hi-only; R11: writes CS pad -> no CS memset):
// Fourier sums via MFMA with angle addition k=8q+r (A rows cos/sin(8q a),
// B rows cos/sin(r a); C_{8q+r}=G[2q][2r]-G[2q+1][2r+1],
// S_{8q+r}=G[2q+1][2r]+G[2q][2r+1]). One wave per (el,f); 8KB LDS.
__global__ __launch_bounds__(64) void kF(const float* __restrict__ MT,
                                         const float* __restrict__ hdr,
                                         _Float16* __restrict__ CS) {
  __shared__ __align__(16) _Float16 Ah[16 * 128];
  __shared__ __align__(16) _Float16 Bh[16 * 128];
  const int lane = threadIdx.x;
  const int el = blockIdx.x >> 8;
  const int f = blockIdx.x & 255;
  const float w1 = hdr[4];
  const float* src = MT + ((size_t)el * F_ + f) * S_;
  _Float16* csrow = CS + ((size_t)el * F_ + f) * CSW;

  // constant rows, once: A q=0 (cos0=1,sin0=0); A rows 14,15 zero; B r=0.
  stpk(Ah, 0, lane, 1.f, 1.f);
  stpk(Ah, 1, lane, 0.f, 0.f);
  stpk(Ah, 14, lane, 0.f, 0.f);
  stpk(Ah, 15, lane, 0.f, 0.f);
  stpk(Bh, 0, lane, 1.f, 1.f);
  stpk(Bh, 1, lane, 0.f, 0.f);

  f32x4v acc = (f32x4v){0.f, 0.f, 0.f, 0.f};
  const int rw = lane & 15, quad = lane >> 4;

  float2 nxt = ((const float2*)src)[lane];
  for (int bt = 0; bt < 8; ++bt) {        // 8 batches x 128 samples
    float2 cur = nxt;
    if (bt < 7) nxt = ((const float2*)src)[(bt + 1) * 64 + lane];
    // two samples (2*lane, 2*lane+1) in lockstep; pack pairs into b32 writes
    float aa = w1 * cur.x, ab = w1 * cur.y;
    float s1a, c1a, s1b, c1b;
    __sincosf(aa, &s1a, &c1a);
    __sincosf(ab, &s1b, &c1b);
    const float tca = c1a + c1a, tcb = c1b + c1b;
    stpk_rne(Bh, 2, lane, c1a, c1b);           // r=1 cos
    stpk_rne(Bh, 3, lane, s1a, s1b);           // r=1 sin
    float cpa = c1a, cppa = 1.f, spa = s1a, sppa = 0.f;
    float cpb = c1b, cppb = 1.f, spb = s1b, sppb = 0.f;
    float c2a = 0.f, c2b = 0.f, s2a = 0.f, s2b = 0.f;
#pragma unroll
    for (int rr = 2; rr <= 7; ++rr) {          // Chebyshev: cos/sin(r*a)
      float cna = fmaf(tca, cpa, -cppa);
      float cnb = fmaf(tcb, cpb, -cppb);
      float sna = fmaf(tca, spa, -sppa);
      float snb = fmaf(tcb, spb, -sppb);
      if (rr == 2) { c2a = cna; c2b = cnb; s2a = sna; s2b = snb; }
      stpk_rne(Bh, 2 * rr, lane, cna, cnb);
      stpk_rne(Bh, 2 * rr + 1, lane, sna, snb);
      cppa = cpa; cpa = cna; cppb = cpb; cpb = cnb;
      sppa = spa; spa = sna; sppb = spb; spb = snb;
    }
    // q-side: cos/sin(8a) by doubling from (c2,s2)
    float d2a = c2a + c2a, d2b = c2b + c2b;
    float c4a = fmaf(d2a, c2a, -1.f), c4b = fmaf(d2b, c2b, -1.f);
    float s4a = d2a * s2a, s4b = d2b * s2b;
    float d4a = c4a + c4a, d4b = c4b + c4b;
    float c8a = fmaf(d4a, c4a, -1.f), c8b = fmaf(d4b, c4b, -1.f);
    float s8a = d4a * s4a, s8b = d4b * s4b;
    stpk_rne(Ah, 2, lane, c8a, c8b);           // q=1
    stpk_rne(Ah, 3, lane, s8a, s8b);
    const float tqa = c8a + c8a, tqb = c8b + c8b;
    float qca = c8a, qcpa = 1.f, qsa = s8a, qspa = 0.f;
    float qcb = c8b, qcpb = 1.f, qsb = s8b, qspb = 0.f;
#pragma unroll
    for (int q = 2; q <= 6; ++q) {             // Chebyshev: cos/sin(8q*a)
      float cna = fmaf(tqa, qca, -qcpa);
      float cnb = fmaf(tqb, qcb, -qcpb);
      float sna = fmaf(tqa, qsa, -qspa);
      float snb = fmaf(tqb, qsb, -qspb);
      stpk_rne(Ah, 2 * q, lane, cna, cnb);
      stpk_rne(Ah, 2 * q + 1, lane, sna, snb);
      qcpa = qca; qca = cna; qcpb = qcb; qcb = cnb;
      qspa = qsa; qsa = sna; qspb = qsb; qsb = snb;
    }
    // MFMA over this batch's K=128 (single wave -> no barrier; compiler
    // inserts lgkmcnt waits for the RAW dependency)
#pragma unroll
    for (int kc = 0; kc < 4; ++kc) {
      const int off = rw * 128 + ((kc * 32 + quad * 8) ^ ((rw & 7) << 3));
      half8 af = *(const half8*)(Ah + off);
      half8 bhf = *(const half8*)(Bh + off);
      acc = __builtin_amdgcn_mfma_f32_16x16x32_f16(af, bhf, acc, 0, 0, 0);
    }
  }
  // extraction: lane holds G[4u+i][c], u=lane>>4, c=lane&15.
  // pair col 2r (even lane) with col 2r+1 (odd lane) via shfl_xor(1).
  float a0 = acc[0], a1 = acc[1], a2 = acc[2], a3 = acc[3];
  float p0 = __shfl_xor(a0, 1), p1 = __shfl_xor(a1, 1);
  float p2 = __shfl_xor(a2, 1), p3 = __shfl_xor(a3, 1);
  if ((rw & 1) == 0) {
    const int rr = rw >> 1;
    const int k0v = 16 * quad + rr;        // q = 2u
    const int k1v = 16 * quad + 8 + rr;    // q = 2u+1
    float C0 = a0 - p1, S0 = a1 + p0;      // G[2q][2r]-G[2q+1][2r+1], ...
    float C1 = a2 - p3, S1 = a3 + p2;
    if (k0v == 0) {
      csrow[0] = (_Float16)1024.f;         // DC exact
      csrow[1] = (_Float16)0.f;
    }
    if (k0v >= 1 && k0v <= NH) {
      put_hl(csrow + 2 * k0v, C0);
      put_hl(csrow + 2 * (NH + k0v), S0);
    }
    if (k1v <= NH) {
      put_hl(csrow + 2 * k1v, C1);
      put_hl(csrow + 2 * (NH + k1v), S1);
    }
  }
  // zero the pad columns (194..223) so kR's full-width reads are
  // deterministic without the 4.6MB CS memset. 15 x 4B stores, lanes 0-14.
  if (lane < 15) {
    h2v z;
    z[0] = (__fp16)0.f;
    z[1] = (__fp16)0.f;
    *(h2v*)(csrow + 194 + 2 * lane) = z;
  }
}

// KR: reconstruction GEMM ksum = CS x BT^T via MFMA (7 K-chunks of 32).
// R2: ZERO-LDS / ZERO-BARRIER, direct-fragment-load (16B-aligned rows).
__global__ __launch_bounds__(256) void kR(const _Float16* __restrict__ CS,
                                          const _Float16* __restrict__ BT,
                                          float* __restrict__ OUT) {
  const int tid = threadIdx.x;
  const int wave = tid >> 6, lane = tid & 63;
  const int nn = lane & 15, quad = lane >> 4;
  const int el = blockIdx.x >> 4;
  const int t0 = (blockIdx.x & 15) << 6;

  const _Float16* ab0 = CS + ((size_t)el * F_ + wave * 64 + 0 * 16 + nn) * CSW + quad * 8;
  const _Float16* ab1 = CS + ((size_t)el * F_ + wave * 64 + 1 * 16 + nn) * CSW + quad * 8;
  const _Float16* ab2 = CS + ((size_t)el * F_ + wave * 64 + 2 * 16 + nn) * CSW + quad * 8;
  const _Float16* ab3 = CS + ((size_t)el * F_ + wave * 64 + 3 * 16 + nn) * CSW + quad * 8;
  const _Float16* bb0 = BT + (size_t)(t0 + 0 * 16 + nn) * CSW + quad * 8;
  const _Float16* bb1 = BT + (size_t)(t0 + 1 * 16 + nn) * CSW + quad * 8;
  const _Float16* bb2 = BT + (size_t)(t0 + 2 * 16 + nn) * CSW + quad * 8;
  const _Float16* bb3 = BT + (size_t)(t0 + 3 * 16 + nn) * CSW + quad * 8;

  f32x4v acc[4][4];
#pragma unroll
  for (int ft = 0; ft < 4; ++ft)
#pragma unroll
    for (int tn = 0; tn < 4; ++tn) acc[ft][tn] = (f32x4v){0.f, 0.f, 0.f, 0.f};

  half8 pa[4], pb[4];
  pa[0] = *(const half8*)ab0; pa[1] = *(const half8*)ab1;
  pa[2] = *(const half8*)ab2; pa[3] = *(const half8*)ab3;
  pb[0] = *(const half8*)bb0; pb[1] = *(const half8*)bb1;
  pb[2] = *(const half8*)bb2; pb[3] = *(const half8*)bb3;

#pragma unroll
  for (int kc = 0; kc < CSW / 32; ++kc) {
    half8 af[4], bf[4];
#pragma unroll
    for (int ft = 0; ft < 4; ++ft) af[ft] = pa[ft];
#pragma unroll
    for (int tn = 0; tn < 4; ++tn) bf[tn] = pb[tn];
    if (kc < CSW / 32 - 1) {
      const int o = (kc + 1) * 32;
      pa[0] = *(const half8*)(ab0 + o); pa[1] = *(const half8*)(ab1 + o);
      pa[2] = *(const half8*)(ab2 + o); pa[3] = *(const half8*)(ab3 + o);
      pb[0] = *(const half8*)(bb0 + o); pb[1] = *(const half8*)(bb1 + o);
      pb[2] = *(const half8*)(bb2 + o); pb[3] = *(const half8*)(bb3 + o);
    }
#pragma unroll
    for (int ft = 0; ft < 4; ++ft)
#pragma unroll
      for (int tn = 0; tn < 4; ++tn)
        acc[ft][tn] = __builtin_amdgcn_mfma_f32_16x16x32_f16(af[ft], bf[tn], acc[ft][tn], 0, 0, 0);
  }

  float* Ob = OUT + (size_t)el * F_ * T_ + t0;
#pragma unroll
  for (int ft = 0; ft < 4; ++ft)
#pragma unroll
    for (int tn = 0; tn < 4; ++tn) {
      f32x4v c = acc[ft][tn];
      const int fb = wave * 64 + ft * 16 + quad * 4;
      const int tc = tn * 16 + nn;
      Ob[(size_t)(fb + 0) * T_ + tc] = c[0];
      Ob[(size_t)(fb + 1) * T_ + tc] = c[1];
      Ob[(size_t)(fb + 2) * T_ + tc] = c[2];
      Ob[(size_t)(fb + 3) * T_ + tc] = c[3];
    }
}

// K4: epilogue (unchanged, validated).
__global__ __launch_bounds__(256) void k4_epi(const float* __restrict__ OUT,
                                              const float* __restrict__ hdr,
                                              const float* __restrict__ dl,
                                              float* __restrict__ out) {
  __shared__ float rs[4][6];
  const int tid = threadIdx.x;
  const int l = blockIdx.x >> 8;
  const int f = blockIdx.x & 255;
  const float left = hdr[0], dg = hdr[1], scale = hdr[3];
  const int t = 4 * tid;
  float etv[4];
#pragma unroll
  for (int d = 0; d < 4; ++d) {
    float x = left + (float)(t + d) * dg;
    etv[d] = expf(-8.0f * x * x);
  }
  float red[E_][4];
#pragma unroll
  for (int e = 0; e < E_; ++e) {
    float4 ks = *(const float4*)(OUT + (((size_t)(e * L_ + l)) * F_ + f) * T_ + t);
    const float dlv = dl[e * L_ + l];
    const float zc = (float)S_ - dlv;
    const float idl = 1.0f / dlv;
    red[e][0] = (ks.x - zc * etv[0]) * idl;
    red[e][1] = (ks.y - zc * etv[1]) * idl;
    red[e][2] = (ks.z - zc * etv[2]) * idl;
    red[e][3] = (ks.w - zc * etv[3]) * idl;
  }
  float D[6];
  const int pa[6] = {0, 0, 0, 1, 1, 2};
  const int pb[6] = {1, 2, 3, 2, 3, 3};
#pragma unroll
  for (int p = 0; p < 6; ++p) {
    float s = 0.f;
#pragma unroll
    for (int d = 0; d < 4; ++d) s += fabsf(red[pa[p]][d] - red[pb[p]][d]);
    D[p] = s;
  }
#pragma unroll
  for (int off = 32; off; off >>= 1)
#pragma unroll
    for (int p = 0; p < 6; ++p) D[p] += __shfl_down(D[p], off);
  if ((tid & 63) == 0) {
#pragma unroll
    for (int p = 0; p < 6; ++p) rs[tid >> 6][p] = D[p];
  }
  __syncthreads();
  if (tid == 0) {
    float Tp[6];
#pragma unroll
    for (int p = 0; p < 6; ++p)
      Tp[p] = (rs[0][p] + rs[1][p] + rs[2][p] + rs[3][p]) * scale;
    float test = Tp[0];
#pragma unroll
    for (int p = 1; p < 6; ++p) test = fmaxf(test, Tp[p]);
    float train = fmaxf(fmaxf(Tp[1], Tp[2]), Tp[5]);
    out[l * F_ + f] = train;
    out[L_ * F_ + l * F_ + f] = test;
  }
}

extern "C" void kernel_launch(void* const* d_in, const int* in_sizes, int n_in,
                              void* d_out, int out_size, void* d_ws, size_t ws_size,
                              hipStream_t stream) {
  const float* A  = (const float*)d_in[0];   // matrix (4,10,1024,256)
  const float* dl = (const float*)d_in[1];   // data_len (4,10)
  const float* P  = (const float*)d_in[2];   // params (256,256)
  float* out = (float*)d_out;
  float* ws = (float*)d_ws;
  float* hdr = ws;
  float* pmin = ws + OFF_PMIN;               // 640 per-block minima
  float* pmax = ws + OFF_PMAX;               // 640 per-block maxima
  float* MT  = ws + OFF_M;                   // fp32 GEMM result (dead after kF)
  float* OUT = ws + OFF_M;                   // OUT aliases MT
  _Float16* CS = (_Float16*)(ws + OFF_CS);
  _Float16* BT = (_Float16*)(ws + OFF_BT);
  _Float16* PT = (_Float16*)(ws + OFF_PT);

  // No memsets (R11, kept): PT fully written by k_pt; BT fully written by
  // kB; CS live region + pad cols written by kF; pmin/pmax fully written
  // by k0 before k1 reads.
  k_pt<<<F_, 256, 0, stream>>>(P, PT);
  k0_mfma<<<NBLK, 256, 0, stream>>>(A, PT, MT, pmin, pmax);
  k1_setup<<<1, 256, 0, stream>>>(pmin, pmax, hdr);
  kB<<<T_, 256, 0, stream>>>(hdr, BT);
  kF<<<E_ * L_ * F_, 64, 0, stream>>>(MT, hdr, CS);   // one wave per (el,f)
  kR<<<(E_ * L_) * 16, 256, 0, stream>>>(CS, BT, OUT);
  k4_epi<<<L_ * F_, 256, 0, stream>>>(OUT, hdr, dl, out);
}